// Round 4
// baseline (386.976 us; speedup 1.0000x reference)
//
#include <hip/hip_runtime.h>
#include <hip/hip_cooperative_groups.h>

namespace cg = cooperative_groups;

#define IN_CH 128
#define OUT_CH 64
#define NEG_SLOPE 0.2f

#define BSHIFT 10       // 1024 nodes per partition
#define CEDGE 2304      // edges per bin chunk (9 units of 256)
#define CAPMAX 36864    // records per partition region (mean 32.7K + ~23 sigma)
// p0 stored as 22-bit fixed point; u64 accumulate = (cnt<<32) | sum(fx22).
#define FIX22 4194304.0f

typedef short bf16x8 __attribute__((ext_vector_type(8)));
typedef float f32x4 __attribute__((ext_vector_type(4)));
typedef unsigned long long u64;
typedef unsigned int u32;

__device__ __forceinline__ unsigned short f2bf(float f) {
  union { float f; unsigned u; } v;
  v.f = f;
  unsigned r = v.u + 0x7FFF + ((v.u >> 16) & 1);  // RNE
  return (unsigned short)(r >> 16);
}

__device__ __forceinline__ float bf2f(unsigned short h) {
  union { unsigned u; float f; } v;
  v.u = (unsigned)h << 16;
  return v.f;
}

// ---------------------------------------------------------------------------
// Single cooperative kernel, 4 phases separated by grid.sync():
//  A prep: lwt transpose + u table + zero gcur.
//  B score: si/sj/wself per node, seed wsum64=0.
//  C role-split: blocks [0,nbin) counting-sort 2304-edge chunks into 49
//    dst-range partitions (batched 9-edge/thread passes: edst kept in regs
//    across hist+score, all si/sj gathers in flight together); blocks
//    [nbin,G) run the bf16 MFMA GEMM into xhb (overlap hides in bin stalls).
//  D reduce+out: block (p,q) filters partition p's records for sub-bucket q
//    into a 256-entry u64 LDS table, then writes out 256 nodes.
// ---------------------------------------------------------------------------
__global__ __launch_bounds__(256, 4) void fused_kernel(
    const float* __restrict__ x, const float* __restrict__ emb,
    const float* __restrict__ lw, const float* __restrict__ att_i,
    const float* __restrict__ att_j, const float* __restrict__ aei,
    const float* __restrict__ aej, const int* __restrict__ esrc,
    const int* __restrict__ edst, float* __restrict__ out,
    u64* __restrict__ wsum64, float2* __restrict__ si,
    float2* __restrict__ sj, float* __restrict__ wself,
    float* __restrict__ u, unsigned short* __restrict__ lwt,
    unsigned short* __restrict__ xhb, int* __restrict__ gcur,
    u32* __restrict__ brecs, int cap, int N, int E, int nbin, int nchunk,
    int nred) {
  cg::grid_group grid = cg::this_grid();
  __shared__ u32 recs[CEDGE];  // 9 KB
  __shared__ int hist[64], scn[64], gbase[64], cur[64];
  __shared__ u64 tab[256];     // 2 KB

  const int G = gridDim.x;
  const int bid = blockIdx.x;
  const int tid = threadIdx.x;
  const int wave = tid >> 6;
  const int lane = tid & 63;

  // ============================ Phase A: prep ============================
  for (int vb = bid; vb < 66; vb += G) {
    if (vb < 64) {
      int idx = vb * 256 + tid;  // 0..16383
      int k = idx >> 7;
      int c = idx & 127;
      lwt[(size_t)c * IN_CH + k] = f2bf(lw[idx]);
    } else {
      int which = vb - 64;  // 0 -> att_i, 1 -> att_j
      const float* att = which ? att_j : att_i;
      int k = tid & 127;
      int h = (tid >> 7) & 1;
      float v = 0.f;
#pragma unroll 8
      for (int d = 0; d < 64; ++d)
        v = fmaf(lw[(size_t)k * IN_CH + h * 64 + d], att[h * 64 + d], v);
      u[which * 256 + h * 128 + k] = v;
    }
  }
  if (bid == 0) gcur[tid] = 0;
  grid.sync();

  // ============================ Phase B: score ===========================
  for (int n = bid * 4 + wave; n < N; n += G * 4) {
    float x0 = x[(size_t)n * IN_CH + lane];
    float x1 = x[(size_t)n * IN_CH + 64 + lane];
    float em = emb[(size_t)n * OUT_CH + lane];

    float v_si0 = fmaf(x0, u[lane], fmaf(x1, u[64 + lane], em * aei[lane]));
    float v_si1 =
        fmaf(x0, u[128 + lane], fmaf(x1, u[192 + lane], em * aei[64 + lane]));
    float v_sj0 =
        fmaf(x0, u[256 + lane], fmaf(x1, u[320 + lane], em * aej[lane]));
    float v_sj1 =
        fmaf(x0, u[384 + lane], fmaf(x1, u[448 + lane], em * aej[64 + lane]));

#pragma unroll
    for (int off = 32; off > 0; off >>= 1) {
      v_si0 += __shfl_xor(v_si0, off, 64);
      v_si1 += __shfl_xor(v_si1, off, 64);
      v_sj0 += __shfl_xor(v_sj0, off, 64);
      v_sj1 += __shfl_xor(v_sj1, off, 64);
    }

    if (lane == 0) {
      si[n] = make_float2(v_si0, v_si1);
      sj[n] = make_float2(v_sj0, v_sj1);
      float a0 = v_si0 + v_sj0;
      float a1 = v_si1 + v_sj1;
      a0 = a0 > 0.f ? a0 : NEG_SLOPE * a0;
      a1 = a1 > 0.f ? a1 : NEG_SLOPE * a1;
      wself[n] = 1.f / (1.f + __expf(a1 - a0));
      wsum64[n] = 0ull;  // spill-fallback baseline
    }
  }
  grid.sync();

  // ===================== Phase C: bin || gemm role split =================
  if (bid < nbin) {
    // ---- bin role: grid-stride over 2304-edge chunks ----
    for (int c = bid; c < nchunk; c += nbin) {
      const long e0 = (long)c * CEDGE;
      const int cnt = (int)min((long)CEDGE, (long)E - e0);
      const int kcnt = (cnt + 255) >> 8;

      if (tid < 64) hist[tid] = 0;
      __syncthreads();

      // batched edge-index load (edst kept in regs across both passes)
      int dv[9];
#pragma unroll
      for (int k = 0; k < 9; ++k) {
        long e = e0 + (k << 8) + tid;
        dv[k] = (k < kcnt && e < E) ? edst[e] : -1;
      }
#pragma unroll
      for (int k = 0; k < 9; ++k)
        if (dv[k] >= 0) atomicAdd(&hist[dv[k] >> BSHIFT], 1);
      __syncthreads();

      // wave-0 shuffle prefix scan over 64 partitions
      if (tid < 64) {
        int h = hist[tid];
        int v = h;
#pragma unroll
        for (int off = 1; off < 64; off <<= 1) {
          int t = __shfl_up(v, off, 64);
          if (tid >= off) v += t;
        }
        int excl = v - h;
        scn[tid] = excl;
        cur[tid] = excl;
        gbase[tid] = (h > 0) ? atomicAdd(&gcur[tid], h) : 0;
      }
      __syncthreads();

      // batched gathers: all si/sj loads in flight together
      float2 av[9], bv[9];
#pragma unroll
      for (int k = 0; k < 9; ++k) {
        if (dv[k] >= 0) {
          long e = e0 + (k << 8) + tid;
          av[k] = si[esrc[e]];
          bv[k] = sj[dv[k]];
        }
      }
#pragma unroll
      for (int k = 0; k < 9; ++k) {
        if (dv[k] >= 0) {
          float a0 = av[k].x + bv[k].x;
          float a1 = av[k].y + bv[k].y;
          a0 = a0 > 0.f ? a0 : NEG_SLOPE * a0;
          a1 = a1 > 0.f ? a1 : NEG_SLOPE * a1;
          float p0 = 1.f / (1.f + __expf(a1 - a0));
          u32 fx = (u32)fminf(p0 * FIX22 + 0.5f, 4194303.0f);  // 22-bit
          int pos = atomicAdd(&cur[dv[k] >> BSHIFT], 1);
          recs[pos] = ((u32)(dv[k] & 1023) << 22) | fx;
        }
      }
      __syncthreads();

      // coalesced writeout; partition via 6-iter binary search over scn
#pragma unroll
      for (int k = 0; k < 9; ++k) {
        int p = (k << 8) + tid;
        if (k < kcnt && p < cnt) {
          int lo = 0, hi = 63;
#pragma unroll
          for (int it = 0; it < 6; ++it) {
            int mid = (lo + hi + 1) >> 1;
            if (scn[mid] <= p) lo = mid; else hi = mid - 1;
          }
          int b = lo;
          int gofs = gbase[b] + (p - scn[b]);
          u32 rec = recs[p];
          if (gofs < cap) {
            brecs[(size_t)b * cap + gofs] = rec;
          } else {  // rare spill: packed u64 device atomic
            atomicAdd(&wsum64[(b << BSHIFT) + (int)(rec >> 22)],
                      (1ull << 32) | (u64)(rec & 0x3FFFFFu));
          }
        }
      }
      __syncthreads();  // recs/hist reused next chunk
    }
  } else {
    // ---- gemm role (no LDS use): xhb(bf16) = x @ lin_w ----
    const int g = bid - nbin;
    const int ngemm = G - nbin;
    const int ntiles = (N + 63) / 64;
    const int ko = (lane >> 4) * 8;
    const int ccol = lane & 15;
    for (int tile = g; tile < ntiles; tile += ngemm) {
      const int row0 = tile * 64 + wave * 16;
      int arow = row0 + (lane & 15);
      if (arow >= N) arow = N - 1;  // clamped read; stores guarded
      const float* ap = x + (size_t)arow * IN_CH + ko;
      bf16x8 a[4];
#pragma unroll
      for (int kb = 0; kb < 4; ++kb) {
        float4 f0 = *(const float4*)(ap + kb * 32);
        float4 f1 = *(const float4*)(ap + kb * 32 + 4);
        bf16x8 t;
        t[0] = (short)f2bf(f0.x); t[1] = (short)f2bf(f0.y);
        t[2] = (short)f2bf(f0.z); t[3] = (short)f2bf(f0.w);
        t[4] = (short)f2bf(f1.x); t[5] = (short)f2bf(f1.y);
        t[6] = (short)f2bf(f1.z); t[7] = (short)f2bf(f1.w);
        a[kb] = t;
      }
      const int crow0 = row0 + (lane >> 4) * 4;
#pragma unroll
      for (int nt = 0; nt < 8; ++nt) {
        f32x4 acc = {0.f, 0.f, 0.f, 0.f};
        const bf16x8* bp =
            (const bf16x8*)(lwt + (size_t)(nt * 16 + ccol) * IN_CH + ko);
        acc = __builtin_amdgcn_mfma_f32_16x16x32_bf16(a[0], bp[0], acc, 0, 0, 0);
        acc = __builtin_amdgcn_mfma_f32_16x16x32_bf16(a[1], bp[4], acc, 0, 0, 0);
        acc = __builtin_amdgcn_mfma_f32_16x16x32_bf16(a[2], bp[8], acc, 0, 0, 0);
        acc = __builtin_amdgcn_mfma_f32_16x16x32_bf16(a[3], bp[12], acc, 0, 0, 0);
#pragma unroll
        for (int rr = 0; rr < 4; ++rr) {
          int n = crow0 + rr;
          if (n < N) xhb[(size_t)n * IN_CH + nt * 16 + ccol] = f2bf(acc[rr]);
        }
      }
    }
  }
  grid.sync();

  // ========================= Phase D: reduce + out =======================
  for (int m = bid; m < nred; m += G) {
    const int p = m >> 2;   // partition
    const int q = m & 3;    // 256-node sub-bucket
    tab[tid] = 0ull;
    __syncthreads();

    const int cnt = min(gcur[p], cap);
    const u32* rp = brecs + (size_t)p * cap;
#pragma unroll 4
    for (int r = tid; r < cnt; r += 256) {
      u32 rec = rp[r];
      if ((int)(rec >> 30) == q)
        atomicAdd(&tab[(rec >> 22) & 255],
                  (1ull << 32) | (u64)(rec & 0x3FFFFFu));
    }
    __syncthreads();

    const int n0 = (p << BSHIFT) + (q << 8);
    const int nmax = min(256, N - n0);
    if (nmax > 0) {
      for (int t = tid; t < nmax * 16; t += 256) {
        int ln = t >> 4;
        int n = n0 + ln;
        int c4 = (t & 15) << 2;
        u64 acc = tab[ln] + wsum64[n];  // spill baseline shares packing
        float cnt_f = (float)(u32)(acc >> 32);
        float s0 = (float)(u32)(acc & 0xFFFFFFFFu) * (1.0f / FIX22);
        float ps = wself[n];
        float w0 = 0.5f * (s0 + ps);
        float w1 = 0.5f * ((cnt_f - s0) + (1.f - ps));
        ushort4 h0 = *(const ushort4*)&xhb[(size_t)n * IN_CH + c4];
        ushort4 h1 = *(const ushort4*)&xhb[(size_t)n * IN_CH + 64 + c4];
        float4 o;
        o.x = fmaf(bf2f(h0.x), w0, bf2f(h1.x) * w1);
        o.y = fmaf(bf2f(h0.y), w0, bf2f(h1.y) * w1);
        o.z = fmaf(bf2f(h0.z), w0, bf2f(h1.z) * w1);
        o.w = fmaf(bf2f(h0.w), w0, bf2f(h1.w) * w1);
        *(float4*)&out[(size_t)n * OUT_CH + c4] = o;
      }
    }
    __syncthreads();  // tab reused next m
  }
}

extern "C" void kernel_launch(void* const* d_in, const int* in_sizes, int n_in,
                              void* d_out, int out_size, void* d_ws,
                              size_t ws_size, hipStream_t stream) {
  const float* x = (const float*)d_in[0];
  const float* emb = (const float*)d_in[1];
  const float* lw = (const float*)d_in[2];
  const float* att_i = (const float*)d_in[3];
  const float* att_j = (const float*)d_in[4];
  const float* aei = (const float*)d_in[5];
  const float* aej = (const float*)d_in[6];
  const int* esrc = (const int*)d_in[7];
  const int* edst = (const int*)d_in[8];
  float* out = (float*)d_out;

  int N = in_sizes[0] / IN_CH;  // 50000
  int E = in_sizes[7];          // 1600000
  int nbkt = (N + 1023) >> BSHIFT;     // 49 dst partitions
  int nchunk = (E + CEDGE - 1) / CEDGE;  // 695 chunks
  int nred = nbkt * 4;                 // 196 reduce blocks

  char* ws = (char*)d_ws;
  u64* wsum64 = (u64*)ws;                            // N u64
  float2* si = (float2*)(wsum64 + N);                // N float2
  float2* sj = si + N;                               // N float2
  float* wself = (float*)(sj + N);                   // N f32
  float* u = wself + N;                              // 512 f32
  unsigned short* lwt = (unsigned short*)(u + 512);  // 16384 bf16 (32 KB)
  unsigned short* xhb = lwt + 16384;                 // N*128 bf16 (12.8 MB)
  int* gcur = (int*)(xhb + (size_t)N * IN_CH);       // 256 ints
  u32* brecs = (u32*)(gcur + 256);                   // nbkt * cap u32 records

  size_t fixed = (size_t)((char*)brecs - ws);
  size_t avail = ws_size > fixed ? (ws_size - fixed) / 4 : 0;
  int cap = (int)(avail / (nbkt > 0 ? nbkt : 1));
  if (cap > CAPMAX) cap = CAPMAX;
  if (cap < 4096) cap = 4096;  // spill fallback keeps this correct anyway

  // Co-resident grid size (host-side query only; no stream ops).
  static int bpc = 0;
  if (bpc == 0) {
    int nb = 0;
    hipError_t err =
        hipOccupancyMaxActiveBlocksPerMultiprocessor(&nb, fused_kernel, 256, 0);
    if (err != hipSuccess || nb <= 0) nb = 4;
    bpc = nb > 4 ? 4 : nb;
  }
  int G = 256 * bpc;            // 1024 expected
  int nbin = (G * 3) >> 2;      // 768 bin blocks, rest gemm

  void* args[] = {(void*)&x,     (void*)&emb,    (void*)&lw,
                  (void*)&att_i, (void*)&att_j,  (void*)&aei,
                  (void*)&aej,   (void*)&esrc,   (void*)&edst,
                  (void*)&out,   (void*)&wsum64, (void*)&si,
                  (void*)&sj,    (void*)&wself,  (void*)&u,
                  (void*)&lwt,   (void*)&xhb,    (void*)&gcur,
                  (void*)&brecs, (void*)&cap,    (void*)&N,
                  (void*)&E,     (void*)&nbin,   (void*)&nchunk,
                  (void*)&nred};
  hipLaunchCooperativeKernel((void*)fused_kernel, dim3(G), dim3(256), args, 0,
                             stream);
}